// Round 6
// baseline (491.172 us; speedup 1.0000x reference)
//
#include <hip/hip_runtime.h>
#include <math.h>

#define BB 8
#define CC 512
#define KK 19
#define HWHW 16384
#define INV_HW (1.0f/16384.0f)

typedef __attribute__((ext_vector_type(8))) short bf16x8;
typedef __attribute__((ext_vector_type(4))) short s16x4;
typedef __attribute__((ext_vector_type(4))) float f32x4;

__device__ __forceinline__ unsigned short f2bf(float f) {
    unsigned int u = __float_as_uint(f);
    u = (u + 0x7fffu + ((u >> 16) & 1u)) >> 16;
    return (unsigned short)u;
}

// pack 2 floats -> 2 bf16 (RNE, identical to f2bf) in one instruction
__device__ __forceinline__ unsigned int pk_bf16(float a, float b) {
    unsigned int r;
    asm("v_cvt_pk_bf16_f32 %0, %1, %2" : "=v"(r) : "v"(a), "v"(b));
    return r;
}

// ============ k_s12: FUSED mask-GEMM + sigmoid + masked pooling =============
// Occupancy-first restructure of R5: LDS 153K -> 57K (wm 20K + 32K chunk dbuf
// + 5K mask) => 2 blocks/CU, 4 waves/SIMD (R5 had 1 block/CU, 2 waves/SIMD —
// no co-resident block to cover staging stalls). Pass A streams 8 chunks of
// [64c][128p] through the dbuf: mask-MFMA + coalesced relay-out to xt4g
// (byte image identical to R3/R5, consumed by k_s4). Pass B re-reads the
// just-written relay chunks (L2-hot, same CU) and pools via the proven
// inverse-swizzle gather. Each block owns 4 p-tiles -> cf_part 32 partials.
// Tile element map: off(p,c) = (p<<6) + (((c>>3)^(p&7))<<3) + (c&7).
__global__ __launch_bounds__(512, 4) void k_s12(const float* __restrict__ x,
                                                const float* __restrict__ Wm,
                                                const float* __restrict__ bm,
                                                float* __restrict__ cf_part,
                                                unsigned short* __restrict__ xt4g) {
    __shared__ short wm[20 * CC];      // 20 KB
    __shared__ short xc[2][8192];      // 32 KB: dbuf chunk [128p][64c]
    __shared__ short mlds[20 * 128];   // 5 KB: mask [k][p] swizzled, row19=0
    const int tid = threadIdx.x;
    const int b = blockIdx.x >> 5;
    const int ptg = blockIdx.x & 31;

    const int wv = tid >> 6, ln = tid & 63;
    const int lm = ln & 15, q = ln >> 4;

    // wm staging (once per block)
    for (int u = tid; u < 20 * 128; u += 512) {
        const int k = u >> 7;
        const int c4 = (u & 127) << 2;
        float4 w = {0.f, 0.f, 0.f, 0.f};
        if (k < KK) w = *(const float4*)(Wm + k * CC + c4);
        s16x4 v = { (short)f2bf(w.x), (short)f2bf(w.y), (short)f2bf(w.z), (short)f2bf(w.w) };
        *(s16x4*)&wm[(k << 9) + (((c4 >> 3) ^ (k & 7)) << 3) + (c4 & 7)] = v;
    }
    if (tid < 16)  // zero mask row 19 (clamped pad row in pooling A-frags)
        *(uint4*)&mlds[(19 << 7) + (tid << 3)] = make_uint4(0u, 0u, 0u, 0u);

    const f32x4 zz = {0.f, 0.f, 0.f, 0.f};
    // pooling acc: this wave owns (kt = wv>>2, ct = wv&3); one f32x4 per cs.
    // Accumulates over all p of the ptg (4 tiles x 128 p). Static indexing.
    f32x4 pacc[8];
#pragma unroll
    for (int cs = 0; cs < 8; ++cs) pacc[cs] = zz;

    const int cr0 = (tid >> 5) << 2;     // 0..60: base c-row of thread's quad
    const int pA  = (tid & 31) << 2;     // 0..124
    const int cg  = tid >> 5;            // c-quad index 0..15
    const int kt = wv >> 2, ct = wv & 3;
    const int m1 = (lm < 3) ? (16 + lm) : 19;

#pragma unroll
    for (int t = 0; t < 4; ++t) {
        const int pt = (ptg << 2) + t;
        const float* sbase = x + ((size_t)b * CC + cr0) * HWHW + (pt << 7) + pA;
        unsigned short* t4fix = xt4g + ((size_t)((b << 7) | pt) << 16);

        f32x4 acc0 = zz, acc1 = zz;     // mask pre-act for this tile

        float4 Fa[4], Fb[4];
#pragma unroll
        for (int j = 0; j < 4; ++j) Fa[j] = *(const float4*)(sbase + (size_t)j * HWHW);

        // ---- pass A: stream 8 c-chunks: stage -> mask MFMA -> relay ----
#pragma unroll
        for (int cs = 0; cs < 8; ++cs) {
            const float4* cur = (cs & 1) ? Fb : Fa;
            float4* nxt = (cs & 1) ? Fa : Fb;
            if (cs < 7) {                           // issue next chunk EARLY
                const size_t co = (size_t)((cs + 1) << 6) * HWHW;
#pragma unroll
                for (int j = 0; j < 4; ++j)
                    nxt[j] = *(const float4*)(sbase + co + (size_t)j * HWHW);
            }
            short* xts = (short*)xc[cs & 1];
            {
                const float* G0 = (const float*)&cur[0];
                const float* G1 = (const float*)&cur[1];
                const float* G2 = (const float*)&cur[2];
                const float* G3 = (const float*)&cur[3];
#pragma unroll
                for (int jj = 0; jj < 4; ++jj) {    // [p][c]-frag chunk
                    const int pr = pA + jj;
                    uint2 v = make_uint2(pk_bf16(G0[jj], G1[jj]), pk_bf16(G2[jj], G3[jj]));
                    *(uint2*)&xts[(pr << 6) + (((cg >> 1) ^ (pr & 7)) << 3) + ((cg & 1) << 2)] = v;
                }
            }
            __syncthreads();
            // mask-GEMM MFMA: wave's 16-p column slice
#pragma unroll
            for (int ks = 0; ks < 2; ++ks) {
                const int gch = (cs << 3) + (ks << 2) + q;
                bf16x8 a0 = *(const bf16x8*)&wm[(lm << 9) + ((gch ^ (lm & 7)) << 3)];
                bf16x8 a1 = *(const bf16x8*)&wm[(m1 << 9) + ((gch ^ (m1 & 7)) << 3)];
                const int lch = (ks << 2) + q;
                const int pr = (wv << 4) + lm;
                bf16x8 bv = *(const bf16x8*)&xts[(pr << 6) + ((lch ^ (pr & 7)) << 3)];
                acc0 = __builtin_amdgcn_mfma_f32_16x16x32_bf16(a0, bv, acc0, 0, 0, 0);
                acc1 = __builtin_amdgcn_mfma_f32_16x16x32_bf16(a1, bv, acc1, 0, 0, 0);
            }
            // coalesced relay: chunk image -> global (16KB)
            {
                unsigned short* t4 = t4fix + ((size_t)cs << 13);
#pragma unroll
                for (int r = 0; r < 2; ++r) {
                    uint4 v = *(const uint4*)&xts[(r << 12) + (tid << 3)];
                    *(uint4*)(t4 + (r << 12) + (tid << 3)) = v;
                }
            }
            __syncthreads();
        }

        // sigmoid -> bf16 mask tile [k][p] (swizzled) for this tile
        {
            const int prow = (wv << 4) + lm;
#pragma unroll
            for (int mt = 0; mt < 2; ++mt) {
                const f32x4 a = mt ? acc1 : acc0;
#pragma unroll
                for (int r = 0; r < 4; ++r) {
                    const int k = (mt << 4) + (q << 2) + r;
                    if (k < KK) {
                        const float tt = a[r] + bm[k];
                        mlds[(k << 7) + (((prow >> 3) ^ (k & 7)) << 3) + (prow & 7)] =
                            (short)f2bf(1.0f / (1.0f + __expf(-tt)));
                    }
                }
            }
        }
        __syncthreads();

        // ---- pass B: pool from relay chunks (L2-hot re-read) ----
        uint4 Pa[2], Pb[2];
        Pa[0] = *(const uint4*)(t4fix + (tid << 4));
        Pa[1] = *(const uint4*)(t4fix + (tid << 4) + 8);
#pragma unroll
        for (int cs = 0; cs < 8; ++cs) {
            const uint4* curP = (cs & 1) ? Pb : Pa;
            uint4* nxtP = (cs & 1) ? Pa : Pb;
            if (cs < 7) {
                const unsigned short* tp = t4fix + ((size_t)(cs + 1) << 13);
                nxtP[0] = *(const uint4*)(tp + (tid << 4));
                nxtP[1] = *(const uint4*)(tp + (tid << 4) + 8);
            }
            short* xts = (short*)xc[cs & 1];
            *(uint4*)&xts[(tid << 4)] = curP[0];
            *(uint4*)&xts[(tid << 4) + 8] = curP[1];
            __syncthreads();
            // wave (kt,ct): D[k-tile kt][c ct*16+lm] += mask @ x over p=128
            const int cl = (ct << 4) + lm;         // c_local 0..63
#pragma unroll
            for (int kp = 0; kp < 4; ++kp) {
                const int pg = (kp << 2) + q;
                bf16x8 a = (kt == 0)
                    ? *(const bf16x8*)&mlds[(lm << 7) + ((pg ^ (lm & 7)) << 3)]
                    : *(const bf16x8*)&mlds[(m1 << 7) + ((pg ^ (m1 & 7)) << 3)];
                short e[8];
#pragma unroll
                for (int i = 0; i < 8; ++i) {
                    const int p = (kp << 5) + (q << 3) + i;
                    e[i] = xts[(p << 6) + (((cl >> 3) ^ (p & 7)) << 3) + (cl & 7)];
                }
                bf16x8 bv = {e[0], e[1], e[2], e[3], e[4], e[5], e[6], e[7]};
                pacc[cs] = __builtin_amdgcn_mfma_f32_16x16x32_bf16(a, bv, pacc[cs], 0, 0, 0);
            }
            __syncthreads();
        }
    }

    // epilogue: cf_part[ptg][b][k][c]
    float* dst = cf_part + ((size_t)ptg * BB + b) * KK * CC;
#pragma unroll
    for (int cs = 0; cs < 8; ++cs) {
#pragma unroll
        for (int r = 0; r < 4; ++r) {
            const int k = (kt << 4) + (q << 2) + r;
            if (k < KK) dst[k * CC + (cs << 6) + (ct << 4) + lm] = pacc[cs][r];
        }
    }
}

// ========== k_s2r: cf = INV_HW * sum_ptg cf_part (32 partials) ==========
__global__ __launch_bounds__(256) void k_s2r(const float* __restrict__ part,
                                             float* __restrict__ cf) {
    const int i = blockIdx.x * 256 + threadIdx.x;
    if (i >= BB * KK * CC) return;
    const int b = i / (KK * CC);
    const int rem = i - b * (KK * CC);
    float sum = 0.0f;
#pragma unroll 8
    for (int pt = 0; pt < 32; ++pt)
        sum += part[((size_t)pt * BB + b) * KK * CC + rem];
    cf[i] = sum * INV_HW;
}

// ====== k_filters: fil[b,k,o] = sum_c Wf[k,o,c]*cf[b,k,c] + bf[k,o] ======
__global__ __launch_bounds__(256) void k_filters(const float* __restrict__ Wf,
                                                 const float* __restrict__ bf,
                                                 const float* __restrict__ cf,
                                                 float* __restrict__ fil) {
    const int blk = blockIdx.x;
    const int k = blk >> 7;
    const int o = ((blk & 127) << 2) + (threadIdx.x >> 6);
    const int lane = threadIdx.x & 63;
    const float* wrow = Wf + ((size_t)k * CC + o) * CC;

    float acc[BB];
#pragma unroll
    for (int b = 0; b < BB; ++b) acc[b] = 0.0f;
#pragma unroll
    for (int j = 0; j < CC / 64; ++j) {
        const int c = lane + (j << 6);
        const float wv = wrow[c];
#pragma unroll
        for (int b = 0; b < BB; ++b)
            acc[b] += wv * cf[((size_t)b * KK + k) * CC + c];
    }
#pragma unroll
    for (int b = 0; b < BB; ++b) {
#pragma unroll
        for (int off = 32; off > 0; off >>= 1)
            acc[b] += __shfl_down(acc[b], off, 64);
    }
    if (lane == 0) {
        const float bias = bf[k * CC + o];
#pragma unroll
        for (int b = 0; b < BB; ++b)
            fil[((size_t)b * KK + k) * CC + o] = acc[b] + bias;
    }
}

// ================= k_s4: pred = fil[b] @ x, fp32 out ==============
// x comes from xt4g: pre-swizzled 16KB tiles, read contiguously, raw LDS copy.
__global__ __launch_bounds__(256, 3) void k_s4(const unsigned short* __restrict__ xt4g,
                                               const float* __restrict__ fil,
                                               float* __restrict__ out) {
    __shared__ short wm[20 * CC];
    __shared__ short xt[2][128 * 64];
    const int tid = threadIdx.x;
    const int b = blockIdx.x >> 7;
    const int pt = blockIdx.x & 127;
    const int p0 = pt << 7;
    const float* fb = fil + ((size_t)b * KK) * CC;
    const unsigned short* tb = xt4g + ((size_t)((b << 7) | pt) << 16);

    for (int u = tid; u < 20 * 128; u += 256) {
        const int k = u >> 7;
        const int c4 = (u & 127) << 2;
        float4 w = {0.f, 0.f, 0.f, 0.f};
        if (k < KK) w = *(const float4*)(fb + k * CC + c4);
        s16x4 v = { (short)f2bf(w.x), (short)f2bf(w.y), (short)f2bf(w.z), (short)f2bf(w.w) };
        *(s16x4*)&wm[(k << 9) + (((c4 >> 3) ^ (k & 7)) << 3) + (c4 & 7)] = v;
    }

    const int wv = tid >> 6, ln = tid & 63;
    const int lm = ln & 15, q = ln >> 4;
    const f32x4 zz = {0.f, 0.f, 0.f, 0.f};
    f32x4 acc[2][2];
    acc[0][0] = zz; acc[0][1] = zz; acc[1][0] = zz; acc[1][1] = zz;

    uint4 Ta[4], Tb4[4];
#pragma unroll
    for (int r = 0; r < 4; ++r)
        Ta[r] = *(const uint4*)(tb + (r << 11) + (tid << 3));

#pragma unroll
    for (int cs = 0; cs < 8; ++cs) {
        const uint4* cur = (cs & 1) ? Tb4 : Ta;
        uint4* nxt = (cs & 1) ? Ta : Tb4;
        if (cs < 7) {                               // issue next tile EARLY
#pragma unroll
            for (int r = 0; r < 4; ++r)
                nxt[r] = *(const uint4*)(tb + ((size_t)(cs + 1) << 13) + (r << 11) + (tid << 3));
        }
        short* xts = (short*)xt[cs & 1];
#pragma unroll
        for (int r = 0; r < 4; ++r)
            *(uint4*)&xts[(r << 11) + (tid << 3)] = cur[r];
        asm volatile("s_waitcnt lgkmcnt(0)" ::: "memory");
        __builtin_amdgcn_s_barrier();
        asm volatile("" ::: "memory");
#pragma unroll
        for (int ks = 0; ks < 2; ++ks) {
            const int gch = (cs << 3) + (ks << 2) + q;
            const int m1 = (lm < 3) ? (16 + lm) : 19;
            bf16x8 a0 = *(const bf16x8*)&wm[(lm << 9) + ((gch ^ (lm & 7)) << 3)];
            bf16x8 a1 = *(const bf16x8*)&wm[(m1 << 9) + ((gch ^ (m1 & 7)) << 3)];
            const int lch = (ks << 2) + q;
#pragma unroll
            for (int nt = 0; nt < 2; ++nt) {
                const int pr = (((wv << 1) + nt) << 4) + lm;
                bf16x8 bv = *(const bf16x8*)&xts[(pr << 6) + ((lch ^ (pr & 7)) << 3)];
                acc[0][nt] = __builtin_amdgcn_mfma_f32_16x16x32_bf16(a0, bv, acc[0][nt], 0, 0, 0);
                acc[1][nt] = __builtin_amdgcn_mfma_f32_16x16x32_bf16(a1, bv, acc[1][nt], 0, 0, 0);
            }
        }
    }

    float* ob = out + ((size_t)b * KK) * HWHW + p0;
#pragma unroll
    for (int mt = 0; mt < 2; ++mt)
#pragma unroll
        for (int r = 0; r < 4; ++r) {
            const int k = (mt << 4) + (q << 2) + r;
            if (k < KK) {
#pragma unroll
                for (int nt = 0; nt < 2; ++nt) {
                    const int p = (((wv << 1) + nt) << 4) + lm;
                    ob[(size_t)k * HWHW + p] = acc[mt][nt][r];
                }
            }
        }
}

extern "C" void kernel_launch(void* const* d_in, const int* in_sizes, int n_in,
                              void* d_out, int out_size, void* d_ws, size_t ws_size,
                              hipStream_t stream) {
    const float* x  = (const float*)d_in[0];
    const float* Wm = (const float*)d_in[1];
    const float* bm = (const float*)d_in[2];
    const float* Wf = (const float*)d_in[3];
    const float* bf = (const float*)d_in[4];
    float* out = (float*)d_out;

    char* p = (char*)d_ws;
    float* cf_part = (float*)p;                 p += (size_t)32 * BB * KK * CC * 4;  // 9.96 MB
    float* cf  = (float*)p;                     p += (size_t)BB * KK * CC * 4;       // 311 KB
    float* fil = (float*)p;                     p += (size_t)BB * KK * CC * 4;       // 311 KB
    unsigned short* xt4g = (unsigned short*)p;                                       // 134 MB

    k_s12<<<256, 512, 0, stream>>>(x, Wm, bm, cf_part, xt4g);
    k_s2r<<<(BB * KK * CC + 255) / 256, 256, 0, stream>>>(cf_part, cf);
    k_filters<<<KK * 128, 256, 0, stream>>>(Wf, bf, cf, fil);
    k_s4<<<1024, 256, 0, stream>>>(xt4g, fil, out);
}

// Round 7
// 475.168 us; speedup vs baseline: 1.0337x; 1.0337x over previous
//
#include <hip/hip_runtime.h>
#include <math.h>

#define BB 8
#define CC 512
#define KK 19
#define HWHW 16384
#define INV_HW (1.0f/16384.0f)

typedef __attribute__((ext_vector_type(8))) short bf16x8;
typedef __attribute__((ext_vector_type(4))) short s16x4;
typedef __attribute__((ext_vector_type(4))) float f32x4;

__device__ __forceinline__ unsigned short f2bf(float f) {
    unsigned int u = __float_as_uint(f);
    u = (u + 0x7fffu + ((u >> 16) & 1u)) >> 16;
    return (unsigned short)u;
}

// pack 2 floats -> 2 bf16 (RNE, identical to f2bf) in one instruction
__device__ __forceinline__ unsigned int pk_bf16(float a, float b) {
    unsigned int r;
    asm("v_cvt_pk_bf16_f32 %0, %1, %2" : "=v"(r) : "v"(a), "v"(b));
    return r;
}

// lgkm-only barrier: LDS visibility without draining outstanding global
// loads (the __syncthreads vmcnt(0) drain was k_s12's serializer — m97
// mechanism, exposed at 1-2 blocks/CU). sched_barrier per guide rule #18.
#define LGKMBAR() do { \
    asm volatile("s_waitcnt lgkmcnt(0)" ::: "memory"); \
    __builtin_amdgcn_s_barrier(); \
    __builtin_amdgcn_sched_barrier(0); } while (0)

// full drain barrier: relay global stores must be visible before pass B
// re-reads them through the cache hierarchy.
#define VMBAR() do { \
    asm volatile("s_waitcnt vmcnt(0) lgkmcnt(0)" ::: "memory"); \
    __builtin_amdgcn_s_barrier(); \
    __builtin_amdgcn_sched_barrier(0); } while (0)

// ============ k_s12: FUSED mask-GEMM + sigmoid + masked pooling =============
// R7 fixes vs R6 (counters: VALU 4.6%, MFMA 1.9%, occ 21%, 15.5M bank-conf):
//  - grid 512 (2 p-tiles/block) -> 2 blocks/CU actually resident (R6's grid
//    256 was 1 block/CU: no inter-block stall cover).
//  - relaxed lgkm-only barriers, ONE per chunk (dbuf makes trailing bar
//    redundant); prefetch survives barriers. One vmcnt(0) bar per tile
//    (relay -> pass B visibility).
//  - 2-deep register prefetch in both passes.
//  - pass B: padded stride-66-short LDS tile => conflict-free u16 gather
//    (bank = (p*33 + cl/2)%32: q-groups 8 banks apart, cl fills the rest).
// Tile element map (relay): off(p,c) = (p<<6) + (((c>>3)^(p&7))<<3) + (c&7).
__global__ __launch_bounds__(512, 4) void k_s12(const float* __restrict__ x,
                                                const float* __restrict__ Wm,
                                                const float* __restrict__ bm,
                                                float* __restrict__ cf_part,
                                                unsigned short* __restrict__ xt4g) {
    __shared__ short wm[20 * CC];      // 20 KB
    __shared__ short xc[2][8192];      // 32 KB: pass A dbuf / pass B padded tile
    __shared__ short mlds[20 * 128];   // 5 KB: mask [k][p] swizzled, row19=0
    const int tid = threadIdx.x;
    const int b = blockIdx.x >> 6;
    const int ptg = blockIdx.x & 63;

    const int wv = tid >> 6, ln = tid & 63;
    const int lm = ln & 15, q = ln >> 4;

    for (int u = tid; u < 20 * 128; u += 512) {
        const int k = u >> 7;
        const int c4 = (u & 127) << 2;
        float4 w = {0.f, 0.f, 0.f, 0.f};
        if (k < KK) w = *(const float4*)(Wm + k * CC + c4);
        s16x4 v = { (short)f2bf(w.x), (short)f2bf(w.y), (short)f2bf(w.z), (short)f2bf(w.w) };
        *(s16x4*)&wm[(k << 9) + (((c4 >> 3) ^ (k & 7)) << 3) + (c4 & 7)] = v;
    }
    if (tid < 16)
        *(uint4*)&mlds[(19 << 7) + (tid << 3)] = make_uint4(0u, 0u, 0u, 0u);

    const f32x4 zz = {0.f, 0.f, 0.f, 0.f};
    f32x4 pacc[8];
#pragma unroll
    for (int cs = 0; cs < 8; ++cs) pacc[cs] = zz;

    const int cr0 = (tid >> 5) << 2;     // base c-row of thread's quad
    const int pA  = (tid & 31) << 2;     // 0..124
    const int cg  = tid >> 5;            // c-quad index 0..15
    const int kt = wv >> 2, ct = wv & 3;
    const int m1 = (lm < 3) ? (16 + lm) : 19;
    const int pB = tid >> 2;             // pass-B staging p-row
    const int j0 = (tid & 3) << 1;       // pass-B slot pair

#pragma unroll
    for (int t = 0; t < 2; ++t) {
        const int pt = (ptg << 1) + t;
        const float* sbase = x + ((size_t)b * CC + cr0) * HWHW + (pt << 7) + pA;
        unsigned short* t4fix = xt4g + ((size_t)((b << 7) | pt) << 16);

        f32x4 acc0 = zz, acc1 = zz;

        float4 Fa[4], Fb[4], Fc[4];
#pragma unroll
        for (int j = 0; j < 4; ++j) Fa[j] = *(const float4*)(sbase + (size_t)j * HWHW);
#pragma unroll
        for (int j = 0; j < 4; ++j) Fb[j] = *(const float4*)(sbase + (size_t)(64 + j) * HWHW);

        // ---- pass A: 8 chunks: stage -> (bar) -> mask MFMA + relay ----
#pragma unroll
        for (int cs = 0; cs < 8; ++cs) {
            const float4* cur = (cs % 3 == 0) ? Fa : ((cs % 3 == 1) ? Fb : Fc);
            float4* nxt = ((cs + 2) % 3 == 0) ? Fa : (((cs + 2) % 3 == 1) ? Fb : Fc);
            if (cs < 6) {                           // issue cs+2 loads EARLY
                const size_t co = (size_t)((cs + 2) << 6) * HWHW;
#pragma unroll
                for (int j = 0; j < 4; ++j)
                    nxt[j] = *(const float4*)(sbase + co + (size_t)j * HWHW);
            }
            short* xts = (short*)xc[cs & 1];
            {
                const float* G0 = (const float*)&cur[0];
                const float* G1 = (const float*)&cur[1];
                const float* G2 = (const float*)&cur[2];
                const float* G3 = (const float*)&cur[3];
#pragma unroll
                for (int jj = 0; jj < 4; ++jj) {
                    const int pr = pA + jj;
                    uint2 v = make_uint2(pk_bf16(G0[jj], G1[jj]), pk_bf16(G2[jj], G3[jj]));
                    *(uint2*)&xts[(pr << 6) + (((cg >> 1) ^ (pr & 7)) << 3) + ((cg & 1) << 2)] = v;
                }
            }
            LGKMBAR();
#pragma unroll
            for (int ks = 0; ks < 2; ++ks) {
                const int gch = (cs << 3) + (ks << 2) + q;
                bf16x8 a0 = *(const bf16x8*)&wm[(lm << 9) + ((gch ^ (lm & 7)) << 3)];
                bf16x8 a1 = *(const bf16x8*)&wm[(m1 << 9) + ((gch ^ (m1 & 7)) << 3)];
                const int lch = (ks << 2) + q;
                const int pr = (wv << 4) + lm;
                bf16x8 bv = *(const bf16x8*)&xts[(pr << 6) + ((lch ^ (pr & 7)) << 3)];
                acc0 = __builtin_amdgcn_mfma_f32_16x16x32_bf16(a0, bv, acc0, 0, 0, 0);
                acc1 = __builtin_amdgcn_mfma_f32_16x16x32_bf16(a1, bv, acc1, 0, 0, 0);
            }
            {   // coalesced relay: chunk image -> global (16KB)
                unsigned short* t4 = t4fix + ((size_t)cs << 13);
#pragma unroll
                for (int r = 0; r < 2; ++r) {
                    uint4 v = *(const uint4*)&xts[(r << 12) + (tid << 3)];
                    *(uint4*)(t4 + (r << 12) + (tid << 3)) = v;
                }
            }
            // no trailing barrier: dbuf + next chunk's LGKMBAR covers WAR
        }

        VMBAR();   // relay stores visible before pass B re-reads

        // pass B prefetch chunks 0,1 (issued before sigmoid to hide latency)
        uint4 Pa[2], Pb[2], Pc[2];
        Pa[0] = *(const uint4*)(t4fix + (tid << 4));
        Pa[1] = *(const uint4*)(t4fix + (tid << 4) + 8);
        Pb[0] = *(const uint4*)(t4fix + 8192 + (tid << 4));
        Pb[1] = *(const uint4*)(t4fix + 8192 + (tid << 4) + 8);

        // sigmoid -> bf16 mask tile [k][p] (swizzled)
        {
            const int prow = (wv << 4) + lm;
#pragma unroll
            for (int mt = 0; mt < 2; ++mt) {
                const f32x4 a = mt ? acc1 : acc0;
#pragma unroll
                for (int r = 0; r < 4; ++r) {
                    const int k = (mt << 4) + (q << 2) + r;
                    if (k < KK) {
                        const float tt = a[r] + bm[k];
                        mlds[(k << 7) + (((prow >> 3) ^ (k & 7)) << 3) + (prow & 7)] =
                            (short)f2bf(1.0f / (1.0f + __expf(-tt)));
                    }
                }
            }
        }
        LGKMBAR();

        // ---- pass B: pool from relay chunks via padded conflict-free tile --
        short* xp = (short*)xc;          // stride-66-short padded [128][66]
        int* ip = (int*)xp;
        const int cl = (ct << 4) + lm;
#pragma unroll
        for (int cs = 0; cs < 8; ++cs) {
            const uint4* curP = (cs % 3 == 0) ? Pa : ((cs % 3 == 1) ? Pb : Pc);
            uint4* nxtP = ((cs + 2) % 3 == 0) ? Pa : (((cs + 2) % 3 == 1) ? Pb : Pc);
            if (cs < 6) {
                const unsigned short* tp = t4fix + ((size_t)(cs + 2) << 13);
                nxtP[0] = *(const uint4*)(tp + (tid << 4));
                nxtP[1] = *(const uint4*)(tp + (tid << 4) + 8);
            }
            // unswizzle-write 16 shorts into padded tile (≈2-way max)
#pragma unroll
            for (int r = 0; r < 2; ++r) {
                const int cgrp = (j0 + r) ^ (pB & 7);
                const int d = pB * 33 + (cgrp << 2);
                const uint4 v = curP[r];
                ip[d + 0] = v.x; ip[d + 1] = v.y; ip[d + 2] = v.z; ip[d + 3] = v.w;
            }
            LGKMBAR();
            // conflict-free gather + pooling MFMA
#pragma unroll
            for (int kp = 0; kp < 4; ++kp) {
                const int pg = (kp << 2) + q;
                bf16x8 a = (kt == 0)
                    ? *(const bf16x8*)&mlds[(lm << 7) + ((pg ^ (lm & 7)) << 3)]
                    : *(const bf16x8*)&mlds[(m1 << 7) + ((pg ^ (m1 & 7)) << 3)];
                short e[8];
#pragma unroll
                for (int i = 0; i < 8; ++i) {
                    const int p = (kp << 5) + (q << 3) + i;
                    e[i] = xp[p * 66 + cl];
                }
                bf16x8 bv = {e[0], e[1], e[2], e[3], e[4], e[5], e[6], e[7]};
                pacc[cs] = __builtin_amdgcn_mfma_f32_16x16x32_bf16(a, bv, pacc[cs], 0, 0, 0);
            }
            LGKMBAR();   // WAR: next chunk's staging overwrites the tile
        }
    }

    // epilogue: cf_part[ptg][b][k][c]
    float* dst = cf_part + ((size_t)ptg * BB + b) * KK * CC;
#pragma unroll
    for (int cs = 0; cs < 8; ++cs) {
#pragma unroll
        for (int r = 0; r < 4; ++r) {
            const int k = (kt << 4) + (q << 2) + r;
            if (k < KK) dst[k * CC + (cs << 6) + (ct << 4) + lm] = pacc[cs][r];
        }
    }
}

// ========== k_s2r: cf = INV_HW * sum_ptg cf_part (64 partials) ==========
__global__ __launch_bounds__(256) void k_s2r(const float* __restrict__ part,
                                             float* __restrict__ cf) {
    const int i = blockIdx.x * 256 + threadIdx.x;
    if (i >= BB * KK * CC) return;
    const int b = i / (KK * CC);
    const int rem = i - b * (KK * CC);
    float sum = 0.0f;
#pragma unroll 8
    for (int pt = 0; pt < 64; ++pt)
        sum += part[((size_t)pt * BB + b) * KK * CC + rem];
    cf[i] = sum * INV_HW;
}

// ====== k_filters: fil[b,k,o] = sum_c Wf[k,o,c]*cf[b,k,c] + bf[k,o] ======
__global__ __launch_bounds__(256) void k_filters(const float* __restrict__ Wf,
                                                 const float* __restrict__ bf,
                                                 const float* __restrict__ cf,
                                                 float* __restrict__ fil) {
    const int blk = blockIdx.x;
    const int k = blk >> 7;
    const int o = ((blk & 127) << 2) + (threadIdx.x >> 6);
    const int lane = threadIdx.x & 63;
    const float* wrow = Wf + ((size_t)k * CC + o) * CC;

    float acc[BB];
#pragma unroll
    for (int b = 0; b < BB; ++b) acc[b] = 0.0f;
#pragma unroll
    for (int j = 0; j < CC / 64; ++j) {
        const int c = lane + (j << 6);
        const float wv = wrow[c];
#pragma unroll
        for (int b = 0; b < BB; ++b)
            acc[b] += wv * cf[((size_t)b * KK + k) * CC + c];
    }
#pragma unroll
    for (int b = 0; b < BB; ++b) {
#pragma unroll
        for (int off = 32; off > 0; off >>= 1)
            acc[b] += __shfl_down(acc[b], off, 64);
    }
    if (lane == 0) {
        const float bias = bf[k * CC + o];
#pragma unroll
        for (int b = 0; b < BB; ++b)
            fil[((size_t)b * KK + k) * CC + o] = acc[b] + bias;
    }
}

// ================= k_s4: pred = fil[b] @ x, fp32 out ==============
// x comes from xt4g: pre-swizzled 16KB tiles, read contiguously, raw LDS copy.
__global__ __launch_bounds__(256, 3) void k_s4(const unsigned short* __restrict__ xt4g,
                                               const float* __restrict__ fil,
                                               float* __restrict__ out) {
    __shared__ short wm[20 * CC];
    __shared__ short xt[2][128 * 64];
    const int tid = threadIdx.x;
    const int b = blockIdx.x >> 7;
    const int pt = blockIdx.x & 127;
    const int p0 = pt << 7;
    const float* fb = fil + ((size_t)b * KK) * CC;
    const unsigned short* tb = xt4g + ((size_t)((b << 7) | pt) << 16);

    for (int u = tid; u < 20 * 128; u += 256) {
        const int k = u >> 7;
        const int c4 = (u & 127) << 2;
        float4 w = {0.f, 0.f, 0.f, 0.f};
        if (k < KK) w = *(const float4*)(fb + k * CC + c4);
        s16x4 v = { (short)f2bf(w.x), (short)f2bf(w.y), (short)f2bf(w.z), (short)f2bf(w.w) };
        *(s16x4*)&wm[(k << 9) + (((c4 >> 3) ^ (k & 7)) << 3) + (c4 & 7)] = v;
    }

    const int wv = tid >> 6, ln = tid & 63;
    const int lm = ln & 15, q = ln >> 4;
    const f32x4 zz = {0.f, 0.f, 0.f, 0.f};
    f32x4 acc[2][2];
    acc[0][0] = zz; acc[0][1] = zz; acc[1][0] = zz; acc[1][1] = zz;

    uint4 Ta[4], Tb4[4];
#pragma unroll
    for (int r = 0; r < 4; ++r)
        Ta[r] = *(const uint4*)(tb + (r << 11) + (tid << 3));

#pragma unroll
    for (int cs = 0; cs < 8; ++cs) {
        const uint4* cur = (cs & 1) ? Tb4 : Ta;
        uint4* nxt = (cs & 1) ? Ta : Tb4;
        if (cs < 7) {                               // issue next tile EARLY
#pragma unroll
            for (int r = 0; r < 4; ++r)
                nxt[r] = *(const uint4*)(tb + ((size_t)(cs + 1) << 13) + (r << 11) + (tid << 3));
        }
        short* xts = (short*)xt[cs & 1];
#pragma unroll
        for (int r = 0; r < 4; ++r)
            *(uint4*)&xts[(r << 11) + (tid << 3)] = cur[r];
        asm volatile("s_waitcnt lgkmcnt(0)" ::: "memory");
        __builtin_amdgcn_s_barrier();
        asm volatile("" ::: "memory");
#pragma unroll
        for (int ks = 0; ks < 2; ++ks) {
            const int gch = (cs << 3) + (ks << 2) + q;
            const int m1 = (lm < 3) ? (16 + lm) : 19;
            bf16x8 a0 = *(const bf16x8*)&wm[(lm << 9) + ((gch ^ (lm & 7)) << 3)];
            bf16x8 a1 = *(const bf16x8*)&wm[(m1 << 9) + ((gch ^ (m1 & 7)) << 3)];
            const int lch = (ks << 2) + q;
#pragma unroll
            for (int nt = 0; nt < 2; ++nt) {
                const int pr = (((wv << 1) + nt) << 4) + lm;
                bf16x8 bv = *(const bf16x8*)&xts[(pr << 6) + ((lch ^ (pr & 7)) << 3)];
                acc[0][nt] = __builtin_amdgcn_mfma_f32_16x16x32_bf16(a0, bv, acc[0][nt], 0, 0, 0);
                acc[1][nt] = __builtin_amdgcn_mfma_f32_16x16x32_bf16(a1, bv, acc[1][nt], 0, 0, 0);
            }
        }
    }

    float* ob = out + ((size_t)b * KK) * HWHW + p0;
#pragma unroll
    for (int mt = 0; mt < 2; ++mt)
#pragma unroll
        for (int r = 0; r < 4; ++r) {
            const int k = (mt << 4) + (q << 2) + r;
            if (k < KK) {
#pragma unroll
                for (int nt = 0; nt < 2; ++nt) {
                    const int p = (((wv << 1) + nt) << 4) + lm;
                    ob[(size_t)k * HWHW + p] = acc[mt][nt][r];
                }
            }
        }
}

extern "C" void kernel_launch(void* const* d_in, const int* in_sizes, int n_in,
                              void* d_out, int out_size, void* d_ws, size_t ws_size,
                              hipStream_t stream) {
    const float* x  = (const float*)d_in[0];
    const float* Wm = (const float*)d_in[1];
    const float* bm = (const float*)d_in[2];
    const float* Wf = (const float*)d_in[3];
    const float* bf = (const float*)d_in[4];
    float* out = (float*)d_out;

    char* p = (char*)d_ws;
    float* cf_part = (float*)p;                 p += (size_t)64 * BB * KK * CC * 4;  // 19.9 MB
    float* cf  = (float*)p;                     p += (size_t)BB * KK * CC * 4;       // 311 KB
    float* fil = (float*)p;                     p += (size_t)BB * KK * CC * 4;       // 311 KB
    unsigned short* xt4g = (unsigned short*)p;                                       // 134 MB

    k_s12<<<512, 512, 0, stream>>>(x, Wm, bm, cf_part, xt4g);
    k_s2r<<<(BB * KK * CC + 255) / 256, 256, 0, stream>>>(cf_part, cf);
    k_filters<<<KK * 128, 256, 0, stream>>>(Wf, bf, cf, fil);
    k_s4<<<1024, 256, 0, stream>>>(xt4g, fil, out);
}